// Round 1
// baseline (1068.417 us; speedup 1.0000x reference)
//
#include <hip/hip_runtime.h>

// B=131072, T=16, D=2, H=64. 16 rows/wave, 4 waves/block.
// R6 (from R5, 244us): rocprof says VALU-issue-bound (VALUBusy 69%, MfmaUtil 15%, HBM 3%).
//  - gate math f32x2-packed -> v_pk_{fma,add,mul}_f32; gi weights pre-splatted {w,w}
//    in LDS, ystate relaid [comp][row] so ys pair-loads need no movs.
//  - u/tanh rcps fused: hv = [h*S + Ez*(S-2)] / [S*(1+Ez)], S=1+exp2(pre), Ez=exp2(sz)
//    -> 1 rcp instead of 2 per element (exp args clamped at 61 to avoid inf -> NaN).
//  - z-gate B-frags LDS->VGPR (Whz, 32 regs): whhtab reads halved, LDS 38400->32256.
//  - logabsdet: running product of scales, single log at end (was 16 logs/lane).
// launch_bounds(256,4): cap 128 VGPR (est ~116 live), keeps 4 blocks/CU with LDS 32256.
#define BSZ 131072
#define TT  16
#define RPB 64
#define BLK 256

#define NEG_LOG2E  (-1.4426950408889634f)
#define TWO_LOG2E  2.8853900817779268f

typedef __bf16 bf16x8 __attribute__((ext_vector_type(8)));
typedef float  f32x4  __attribute__((ext_vector_type(4)));
typedef float  f32x2  __attribute__((ext_vector_type(2)));

#define MFMA(a,b,c) __builtin_amdgcn_mfma_f32_16x16x32_bf16((a),(b),(c),0,0,0)

static __device__ __forceinline__ f32x2 lo2(f32x4 v){ return __builtin_shufflevector(v, v, 0, 1); }
static __device__ __forceinline__ f32x2 hi2(f32x4 v){ return __builtin_shufflevector(v, v, 2, 3); }

__global__ __launch_bounds__(BLK, 4) void flow6(
    const float* __restrict__ x,     // (B,16,2)
    const float* __restrict__ z,     // (B,64)
    const float* __restrict__ W_ih,  // (192,2)
    const float* __restrict__ W_hh,  // (192,64)
    const float* __restrict__ b_ih,  // (192)
    const float* __restrict__ b_hh,  // (192)
    const float* __restrict__ W1,    // (64,32)
    const float* __restrict__ b1,    // (32)
    const float* __restrict__ W2,    // (32,4)
    const float* __restrict__ b2,    // (4)
    float* __restrict__ y_out,       // (B,16,2)
    float* __restrict__ lad_out)     // (B)
{
  // LDS: 8192 + 4096 + 3072 + 2048 + 9216 + 5120 + 512 = 32256 B
  __shared__ __align__(16) __bf16 whhtab[8*64*8];   // n-gate B-frags (pre-scaled 2log2e)
  __shared__ __align__(16) __bf16 w1tab[4*64*8];    // W1 B-frags
  __shared__ __align__(16) f32x4  giA[192];         // {w0,w0,w1,w1} pre-scaled
  __shared__ __align__(16) f32x4  giB[128];         // {br,br,bz,bz},{bn,bn,0,0}
  __shared__ __align__(16) __bf16 hbuf[RPB*72];     // h bf16, stride 72
  __shared__ __align__(16) __bf16 hidbuf[RPB*40];   // hidden, cols 32..39 = ls pad
  __shared__ __align__(16) float  yst[128];         // y_{t-1} [comp][row]

  const int tid  = threadIdx.x;
  const int lane = tid & 63, wave = tid >> 6;
  const int quad = lane >> 4, n16 = lane & 15;
  const int gb   = blockIdx.x * RPB;
  const f32x4 zero = {0.f,0.f,0.f,0.f};

  // ---------- one-time staging ----------
  if (tid < 192) {  // giA: pre-scaled, pre-splatted pairs
    const int j = tid;
    const float sc = (j < 128) ? NEG_LOG2E : TWO_LOG2E;
    const float w0 = W_ih[2*j]*sc, w1 = W_ih[2*j+1]*sc;
    giA[j] = (f32x4){w0, w0, w1, w1};
  }
  if (tid < 64) {   // giB: bias pairs (r,z fold b_ih+b_hh; n only b_ih -- b_hh_n in cninit)
    const float br = (b_ih[tid]      + b_hh[tid]     ) * NEG_LOG2E;
    const float bz = (b_ih[64 + tid] + b_hh[64 + tid]) * NEG_LOG2E;
    const float bn =  b_ih[128 + tid]                  * TWO_LOG2E;
    giB[tid*2]     = (f32x4){br, br, bz, bz};
    giB[tid*2 + 1] = (f32x4){bn, bn, 0.f, 0.f};
  }
  // whhtab: n-gate frags f = g*2 + kt (pre-scaled 2log2e)
  #pragma unroll
  for (int i = 0; i < 2; ++i) {
    const int f = i*4 + wave;
    const int g = (f >> 1) & 3, kt = f & 1;
    const float* p = W_hh + (size_t)(128 + g*16 + n16)*64 + kt*32 + quad*8;
    bf16x8 v;
    #pragma unroll
    for (int j = 0; j < 8; ++j) v[j] = (__bf16)(p[j]*TWO_LOG2E);
    *(bf16x8*)&whhtab[(f*64 + lane)*8] = v;
  }
  { // w1tab: frag f = c2*2+kt, one per wave (unscaled)
    const int f = wave, c2 = f >> 1, kt = f & 1;
    bf16x8 v;
    #pragma unroll
    for (int j = 0; j < 8; ++j)
      v[j] = (__bf16)W1[(size_t)(kt*32 + quad*8 + j)*32 + c2*16 + n16];
    *(bf16x8*)&w1tab[(f*64 + lane)*8] = v;
  }
  if (tid < 128) yst[tid] = 0.f;
  #pragma unroll
  for (int r4 = 0; r4 < 4; ++r4) {  // z -> hbuf (bf16)
    const int row = (tid >> 4) + r4*16, col = (tid & 15)*4;
    const float4 zv = *(const float4*)&z[(size_t)(gb + row)*64 + col];
    hbuf[row*72 + col+0] = (__bf16)zv.x; hbuf[row*72 + col+1] = (__bf16)zv.y;
    hbuf[row*72 + col+2] = (__bf16)zv.z; hbuf[row*72 + col+3] = (__bf16)zv.w;
  }

  // r- and z-gate B-frags in regs (pre-scaled by -log2e): 64 VGPR
  bf16x8 Whr[4][2], Whz[4][2];
  #pragma unroll
  for (int g = 0; g < 4; ++g)
    #pragma unroll
    for (int kt = 0; kt < 2; ++kt) {
      const float* pr = W_hh + (size_t)(     g*16 + n16)*64 + kt*32 + quad*8;
      const float* pz = W_hh + (size_t)(64 + g*16 + n16)*64 + kt*32 + quad*8;
      bf16x8 vr, vz;
      #pragma unroll
      for (int j = 0; j < 8; ++j) {
        vr[j] = (__bf16)(pr[j]*NEG_LOG2E);
        vz[j] = (__bf16)(pz[j]*NEG_LOG2E);
      }
      Whr[g][kt] = vr; Whz[g][kt] = vz;
    }
  bf16x8 W2f;
  #pragma unroll
  for (int j = 0; j < 8; ++j)
    W2f[j] = (n16 < 4) ? (__bf16)W2[(size_t)(quad*8 + j)*4 + n16] : (__bf16)0.f;

  // h state fp32 C-layout: hst[g][i] = h[quad*4+i][g*16+n16]
  f32x4 hst[4];
  #pragma unroll
  for (int g = 0; g < 4; ++g)
    #pragma unroll
    for (int i = 0; i < 4; ++i)
      hst[g][i] = z[(size_t)(gb + wave*16 + quad*4 + i)*64 + g*16 + n16];
  float bhn[4];   // b_hh n-part, scaled (folded into cn C-init)
  #pragma unroll
  for (int g = 0; g < 4; ++g) bhn[g] = b_hh[128 + g*16 + n16]*TWO_LOG2E;
  const float b1v0 = b1[n16], b1v1 = b1[16 + n16];
  const float b2ln = (n16 < 4) ? b2[n16] : 0.f;

  __syncthreads();  // only barrier

  const int arow = wave*16 + n16;
  bf16x8 a0 = *(const bf16x8*)&hbuf[arow*72 + quad*8];
  bf16x8 a1 = *(const bf16x8*)&hbuf[arow*72 + 32 + quad*8];

  const int erow = wave*16 + (lane & 15);
  const int comp = (lane >> 4) & 1;
  const int wrow = wave*16 + quad*4;
  const float* xp = x + (size_t)(gb + erow)*(TT*2) + comp;
  float*       yp = y_out + (size_t)(gb + erow)*(TT*2) + comp;
  float yc = 0.f, prodS = 1.0f;

  #pragma unroll 1
  for (int t = 0; t < TT; ++t) {
    const float xt = (lane < 32) ? xp[t*2] : 0.f;   // issue global load early
    const f32x2 ys0a = *(const f32x2*)&yst[wrow];        // y0 rows (0,1)
    const f32x2 ys0b = *(const f32x2*)&yst[wrow + 2];    // y0 rows (2,3)
    const f32x2 ys1a = *(const f32x2*)&yst[64 + wrow];   // y1 rows (0,1)
    const f32x2 ys1b = *(const f32x2*)&yst[64 + wrow + 2];

    // ---- GRU per col-group g (scaled domain; all packable math as f32x2) ----
    #pragma unroll
    for (int g = 0; g < 4; ++g) {
      const bf16x8 bn0 = *(const bf16x8*)&whhtab[((g*2    )*64 + lane)*8];
      const bf16x8 bn1 = *(const bf16x8*)&whhtab[((g*2 + 1)*64 + lane)*8];
      f32x4 cr = MFMA(a0, Whr[g][0], zero); cr = MFMA(a1, Whr[g][1], cr);
      f32x4 cz = MFMA(a0, Whz[g][0], zero); cz = MFMA(a1, Whz[g][1], cz);
      const f32x4 cninit = {bhn[g], bhn[g], bhn[g], bhn[g]};
      f32x4 cn = MFMA(a0, bn0, cninit);     cn = MFMA(a1, bn1, cn);

      const f32x4 Ar  = giA[      g*16 + n16];
      const f32x4 Az  = giA[ 64 + g*16 + n16];
      const f32x4 An  = giA[128 + g*16 + n16];
      const f32x4 Bz4 = giB[(g*16 + n16)*2];
      const f32x2 bnp = *(const f32x2*)&giB[(g*16 + n16)*2 + 1];

      #pragma unroll
      for (int m = 0; m < 2; ++m) {
        const f32x2 ys0p = m ? ys0b : ys0a;
        const f32x2 ys1p = m ? ys1b : ys1a;
        const f32x2 crp = m ? hi2(cr) : lo2(cr);
        const f32x2 czp = m ? hi2(cz) : lo2(cz);
        const f32x2 cnp = m ? hi2(cn) : lo2(cn);
        const f32x2 hp  = m ? hi2(hst[g]) : lo2(hst[g]);

        // pre-activations (scaled): sr,sz = -log2e*v; pre = 2log2e*vn
        const f32x2 srp  = lo2(Ar)*ys0p + (hi2(Ar)*ys1p + (crp + lo2(Bz4)));
        const f32x2 szp  = lo2(Az)*ys0p + (hi2(Az)*ys1p + (czp + hi2(Bz4)));
        const f32x2 ginp = lo2(An)*ys0p + (hi2(An)*ys1p + bnp);

        const f32x2 Erp = {__builtin_amdgcn_exp2f(srp.x), __builtin_amdgcn_exp2f(srp.y)};
        const f32x2 drp = Erp + 1.0f;
        const f32x2 rp  = {__builtin_amdgcn_rcpf(drp.x), __builtin_amdgcn_rcpf(drp.y)};
        const f32x2 prep = rp*cnp + ginp;
        // fused tail: hv = [h*S + Ez*(S-2)] / [S*(1+Ez)], S = 1+En
        const f32x2 Ezp = {__builtin_amdgcn_exp2f(fminf(szp.x, 61.f)),
                           __builtin_amdgcn_exp2f(fminf(szp.y, 61.f))};
        const f32x2 Enp = {__builtin_amdgcn_exp2f(fminf(prep.x, 61.f)),
                           __builtin_amdgcn_exp2f(fminf(prep.y, 61.f))};
        const f32x2 Sp   = Enp + 1.0f;
        const f32x2 hpep = hp + Ezp;
        const f32x2 m2ep = Ezp * -2.0f;
        const f32x2 nump = Sp*hpep + m2ep;
        const f32x2 denp = Sp*Ezp + Sp;
        const f32x2 rdp  = {__builtin_amdgcn_rcpf(denp.x), __builtin_amdgcn_rcpf(denp.y)};
        const f32x2 hvp  = nump * rdp;

        hst[g][2*m]   = hvp.x;
        hst[g][2*m+1] = hvp.y;
        hbuf[(wrow + 2*m    )*72 + g*16 + n16] = (__bf16)hvp.x;
        hbuf[(wrow + 2*m + 1)*72 + g*16 + n16] = (__bf16)hvp.y;
      }
    }

    a0 = *(const bf16x8*)&hbuf[arow*72 + quad*8];
    a1 = *(const bf16x8*)&hbuf[arow*72 + 32 + quad*8];

    // ---- MLP1 ----
    #pragma unroll
    for (int c2 = 0; c2 < 2; ++c2) {
      const float bb = c2 ? b1v1 : b1v0;
      const f32x4 binit = {bb, bb, bb, bb};
      f32x4 hc = MFMA(a0, *(const bf16x8*)&w1tab[((c2*2  )*64 + lane)*8], binit);
      hc       = MFMA(a1, *(const bf16x8*)&w1tab[((c2*2+1)*64 + lane)*8], hc);
      #pragma unroll
      for (int i = 0; i < 4; ++i)
        hidbuf[(wrow + i)*40 + c2*16 + n16] = (__bf16)fmaxf(hc[i], 0.f);
    }

    // ---- MLP2: ls -> hidbuf pad (cols 32..39 as 4 floats) ----
    {
      const bf16x8 ha = *(const bf16x8*)&hidbuf[arow*40 + quad*8];
      const f32x4 b2init = {b2ln, b2ln, b2ln, b2ln};
      const f32x4 ls = MFMA(ha, W2f, b2init);
      if (n16 < 4) {
        #pragma unroll
        for (int i = 0; i < 4; ++i)
          ((float*)&hidbuf[(wrow + i)*40 + 32])[n16] = ls[i];
      }
    }

    // ---- epilogue (32 lanes): y update + scale product (log deferred) ----
    if (lane < 32) {
      const float* lsp = (const float*)&hidbuf[erow*40 + 32];
      const float lc = lsp[comp];
      const float l2 = lsp[2 + comp];
      const float s  = __logf(1.0f + __expf(l2)) + 0.001f;
      yc += lc + s * xt;
      prodS *= s;
      yst[comp*64 + erow] = yc;
      yp[t*2] = yc;
    }
  }

  // logabsdet = log(prod_t s_t) per comp, summed over comps (matches reference)
  const float ll  = __logf(prodS);
  const float llo = __shfl(ll, lane ^ 16, 64);
  if (lane < 16) lad_out[gb + wave*16 + lane] = ll + llo;
}

extern "C" void kernel_launch(void* const* d_in, const int* in_sizes, int n_in,
                              void* d_out, int out_size, void* d_ws, size_t ws_size,
                              hipStream_t stream) {
  const float* x    = (const float*)d_in[0];
  const float* z    = (const float*)d_in[1];
  const float* W_ih = (const float*)d_in[2];
  const float* W_hh = (const float*)d_in[3];
  const float* b_ih = (const float*)d_in[4];
  const float* b_hh = (const float*)d_in[5];
  const float* W1   = (const float*)d_in[6];
  const float* b1   = (const float*)d_in[7];
  const float* W2   = (const float*)d_in[8];
  const float* b2   = (const float*)d_in[9];

  float* y_out   = (float*)d_out;
  float* lad_out = y_out + (size_t)BSZ * TT * 2;

  dim3 grid(BSZ / RPB), block(BLK);
  hipLaunchKernelGGL(flow6, grid, block, 0, stream,
                     x, z, W_ih, W_hh, b_ih, b_hh, W1, b1, W2, b2,
                     y_out, lad_out);
}

// Round 2
// 732.713 us; speedup vs baseline: 1.4582x; 1.4582x over previous
//
#include <hip/hip_runtime.h>

// B=131072, T=16, D=2, H=64. 16 rows/wave, 4 waves/block.
// R7 (from R6 post-mortem): R6's launch_bounds(256,4) cap=128 caused catastrophic
// scratch spill (FETCH 25MB->2.7GB, 922us). Math rewrite itself is correct.
//  - bound back to (256,3) (R5's proven no-spill cap ~170);
//  - Whz back to LDS (whhtab holds z+n frags, 16 frags as in R5) -> -32 static VGPR,
//    est ~100 live; occupancy LDS-limited at 4 blocks/CU (16 waves) as R5.
// Kept from R6: f32x2-packed gate math (v_pk_fma/add/mul), pre-splatted gi pairs,
// fused u/tanh tail (1 rcp instead of 2), yst [comp][row], deferred single log.
#define BSZ 131072
#define TT  16
#define RPB 64
#define BLK 256

#define NEG_LOG2E  (-1.4426950408889634f)
#define TWO_LOG2E  2.8853900817779268f

typedef __bf16 bf16x8 __attribute__((ext_vector_type(8)));
typedef float  f32x4  __attribute__((ext_vector_type(4)));
typedef float  f32x2  __attribute__((ext_vector_type(2)));

#define MFMA(a,b,c) __builtin_amdgcn_mfma_f32_16x16x32_bf16((a),(b),(c),0,0,0)

static __device__ __forceinline__ f32x2 lo2(f32x4 v){ return __builtin_shufflevector(v, v, 0, 1); }
static __device__ __forceinline__ f32x2 hi2(f32x4 v){ return __builtin_shufflevector(v, v, 2, 3); }

__global__ __launch_bounds__(BLK, 3) void flow7(
    const float* __restrict__ x,     // (B,16,2)
    const float* __restrict__ z,     // (B,64)
    const float* __restrict__ W_ih,  // (192,2)
    const float* __restrict__ W_hh,  // (192,64)
    const float* __restrict__ b_ih,  // (192)
    const float* __restrict__ b_hh,  // (192)
    const float* __restrict__ W1,    // (64,32)
    const float* __restrict__ b1,    // (32)
    const float* __restrict__ W2,    // (32,4)
    const float* __restrict__ b2,    // (4)
    float* __restrict__ y_out,       // (B,16,2)
    float* __restrict__ lad_out)     // (B)
{
  // LDS: 16384 + 4096 + 3072 + 2048 + 9216 + 5120 + 512 = 40448 B (4 blocks/CU)
  __shared__ __align__(16) __bf16 whhtab[16*64*8];  // z/n-gate B-frags (pre-scaled)
  __shared__ __align__(16) __bf16 w1tab[4*64*8];    // W1 B-frags
  __shared__ __align__(16) f32x4  giA[192];         // {w0,w0,w1,w1} pre-scaled
  __shared__ __align__(16) f32x4  giB[128];         // {br,br,bz,bz},{bn,bn,0,0}
  __shared__ __align__(16) __bf16 hbuf[RPB*72];     // h bf16, stride 72
  __shared__ __align__(16) __bf16 hidbuf[RPB*40];   // hidden, cols 32..39 = ls pad
  __shared__ __align__(16) float  yst[128];         // y_{t-1} [comp][row]

  const int tid  = threadIdx.x;
  const int lane = tid & 63, wave = tid >> 6;
  const int quad = lane >> 4, n16 = lane & 15;
  const int gb   = blockIdx.x * RPB;
  const f32x4 zero = {0.f,0.f,0.f,0.f};

  // ---------- one-time staging ----------
  if (tid < 192) {  // giA: pre-scaled, pre-splatted pairs
    const int j = tid;
    const float sc = (j < 128) ? NEG_LOG2E : TWO_LOG2E;
    const float w0 = W_ih[2*j]*sc, w1 = W_ih[2*j+1]*sc;
    giA[j] = (f32x4){w0, w0, w1, w1};
  }
  if (tid < 64) {   // giB: bias pairs (r,z fold b_ih+b_hh; n only b_ih -- b_hh_n in cninit)
    const float br = (b_ih[tid]      + b_hh[tid]     ) * NEG_LOG2E;
    const float bz = (b_ih[64 + tid] + b_hh[64 + tid]) * NEG_LOG2E;
    const float bn =  b_ih[128 + tid]                  * TWO_LOG2E;
    giB[tid*2]     = (f32x4){br, br, bz, bz};
    giB[tid*2 + 1] = (f32x4){bn, bn, 0.f, 0.f};
  }
  // whhtab: f = (gate-1)*8 + g*2 + kt, gate 1=z (x -log2e), 2=n (x 2log2e)
  #pragma unroll
  for (int i = 0; i < 4; ++i) {
    const int f = i*4 + wave;
    const int gate = 1 + (f >> 3), g = (f >> 1) & 3, kt = f & 1;
    const float sc = (gate == 1) ? NEG_LOG2E : TWO_LOG2E;
    const float* p = W_hh + (size_t)((gate*4 + g)*16 + n16)*64 + kt*32 + quad*8;
    bf16x8 v;
    #pragma unroll
    for (int j = 0; j < 8; ++j) v[j] = (__bf16)(p[j]*sc);
    *(bf16x8*)&whhtab[(f*64 + lane)*8] = v;
  }
  { // w1tab: frag f = c2*2+kt, one per wave (unscaled)
    const int f = wave, c2 = f >> 1, kt = f & 1;
    bf16x8 v;
    #pragma unroll
    for (int j = 0; j < 8; ++j)
      v[j] = (__bf16)W1[(size_t)(kt*32 + quad*8 + j)*32 + c2*16 + n16];
    *(bf16x8*)&w1tab[(f*64 + lane)*8] = v;
  }
  if (tid < 128) yst[tid] = 0.f;
  #pragma unroll
  for (int r4 = 0; r4 < 4; ++r4) {  // z -> hbuf (bf16)
    const int row = (tid >> 4) + r4*16, col = (tid & 15)*4;
    const float4 zv = *(const float4*)&z[(size_t)(gb + row)*64 + col];
    hbuf[row*72 + col+0] = (__bf16)zv.x; hbuf[row*72 + col+1] = (__bf16)zv.y;
    hbuf[row*72 + col+2] = (__bf16)zv.z; hbuf[row*72 + col+3] = (__bf16)zv.w;
  }

  // r-gate B-frags in regs (pre-scaled by -log2e): 32 VGPR
  bf16x8 Whr[4][2];
  #pragma unroll
  for (int g = 0; g < 4; ++g)
    #pragma unroll
    for (int kt = 0; kt < 2; ++kt) {
      const float* p = W_hh + (size_t)(g*16 + n16)*64 + kt*32 + quad*8;
      bf16x8 v;
      #pragma unroll
      for (int j = 0; j < 8; ++j) v[j] = (__bf16)(p[j]*NEG_LOG2E);
      Whr[g][kt] = v;
    }
  bf16x8 W2f;
  #pragma unroll
  for (int j = 0; j < 8; ++j)
    W2f[j] = (n16 < 4) ? (__bf16)W2[(size_t)(quad*8 + j)*4 + n16] : (__bf16)0.f;

  // h state fp32 C-layout: hst[g][i] = h[quad*4+i][g*16+n16]
  f32x4 hst[4];
  #pragma unroll
  for (int g = 0; g < 4; ++g)
    #pragma unroll
    for (int i = 0; i < 4; ++i)
      hst[g][i] = z[(size_t)(gb + wave*16 + quad*4 + i)*64 + g*16 + n16];
  float bhn[4];   // b_hh n-part, scaled (folded into cn C-init)
  #pragma unroll
  for (int g = 0; g < 4; ++g) bhn[g] = b_hh[128 + g*16 + n16]*TWO_LOG2E;
  const float b1v0 = b1[n16], b1v1 = b1[16 + n16];
  const float b2ln = (n16 < 4) ? b2[n16] : 0.f;

  __syncthreads();  // only barrier

  const int arow = wave*16 + n16;
  bf16x8 a0 = *(const bf16x8*)&hbuf[arow*72 + quad*8];
  bf16x8 a1 = *(const bf16x8*)&hbuf[arow*72 + 32 + quad*8];

  const int erow = wave*16 + (lane & 15);
  const int comp = (lane >> 4) & 1;
  const int wrow = wave*16 + quad*4;
  const float* xp = x + (size_t)(gb + erow)*(TT*2) + comp;
  float*       yp = y_out + (size_t)(gb + erow)*(TT*2) + comp;
  float yc = 0.f, prodS = 1.0f;

  #pragma unroll 1
  for (int t = 0; t < TT; ++t) {
    const float xt = (lane < 32) ? xp[t*2] : 0.f;   // issue global load early
    const f32x2 ys0a = *(const f32x2*)&yst[wrow];        // y0 rows (0,1)
    const f32x2 ys0b = *(const f32x2*)&yst[wrow + 2];    // y0 rows (2,3)
    const f32x2 ys1a = *(const f32x2*)&yst[64 + wrow];   // y1 rows (0,1)
    const f32x2 ys1b = *(const f32x2*)&yst[64 + wrow + 2];

    // ---- GRU per col-group g (scaled domain; all packable math as f32x2) ----
    #pragma unroll
    for (int g = 0; g < 4; ++g) {
      const bf16x8 bz0 = *(const bf16x8*)&whhtab[((g*2    )*64 + lane)*8];
      const bf16x8 bz1 = *(const bf16x8*)&whhtab[((g*2 + 1)*64 + lane)*8];
      const bf16x8 bn0 = *(const bf16x8*)&whhtab[((8 + g*2    )*64 + lane)*8];
      const bf16x8 bn1 = *(const bf16x8*)&whhtab[((8 + g*2 + 1)*64 + lane)*8];
      f32x4 cr = MFMA(a0, Whr[g][0], zero); cr = MFMA(a1, Whr[g][1], cr);
      f32x4 cz = MFMA(a0, bz0, zero);       cz = MFMA(a1, bz1, cz);
      const f32x4 cninit = {bhn[g], bhn[g], bhn[g], bhn[g]};
      f32x4 cn = MFMA(a0, bn0, cninit);     cn = MFMA(a1, bn1, cn);

      const f32x4 Ar  = giA[      g*16 + n16];
      const f32x4 Az  = giA[ 64 + g*16 + n16];
      const f32x4 An  = giA[128 + g*16 + n16];
      const f32x4 Bz4 = giB[(g*16 + n16)*2];
      const f32x2 bnp = *(const f32x2*)&giB[(g*16 + n16)*2 + 1];

      #pragma unroll
      for (int m = 0; m < 2; ++m) {
        const f32x2 ys0p = m ? ys0b : ys0a;
        const f32x2 ys1p = m ? ys1b : ys1a;
        const f32x2 crp = m ? hi2(cr) : lo2(cr);
        const f32x2 czp = m ? hi2(cz) : lo2(cz);
        const f32x2 cnp = m ? hi2(cn) : lo2(cn);
        const f32x2 hp  = m ? hi2(hst[g]) : lo2(hst[g]);

        // pre-activations (scaled): sr,sz = -log2e*v; pre = 2log2e*vn
        const f32x2 srp  = lo2(Ar)*ys0p + (hi2(Ar)*ys1p + (crp + lo2(Bz4)));
        const f32x2 szp  = lo2(Az)*ys0p + (hi2(Az)*ys1p + (czp + hi2(Bz4)));
        const f32x2 ginp = lo2(An)*ys0p + (hi2(An)*ys1p + bnp);

        const f32x2 Erp = {__builtin_amdgcn_exp2f(srp.x), __builtin_amdgcn_exp2f(srp.y)};
        const f32x2 drp = Erp + 1.0f;
        const f32x2 rp  = {__builtin_amdgcn_rcpf(drp.x), __builtin_amdgcn_rcpf(drp.y)};
        const f32x2 prep = rp*cnp + ginp;
        // fused tail: hv = [h*S + Ez*(S-2)] / [S*(1+Ez)], S = 1+En
        const f32x2 Ezp = {__builtin_amdgcn_exp2f(fminf(szp.x, 61.f)),
                           __builtin_amdgcn_exp2f(fminf(szp.y, 61.f))};
        const f32x2 Enp = {__builtin_amdgcn_exp2f(fminf(prep.x, 61.f)),
                           __builtin_amdgcn_exp2f(fminf(prep.y, 61.f))};
        const f32x2 Sp   = Enp + 1.0f;
        const f32x2 hpep = hp + Ezp;
        const f32x2 m2ep = Ezp * -2.0f;
        const f32x2 nump = Sp*hpep + m2ep;
        const f32x2 denp = Sp*Ezp + Sp;
        const f32x2 rdp  = {__builtin_amdgcn_rcpf(denp.x), __builtin_amdgcn_rcpf(denp.y)};
        const f32x2 hvp  = nump * rdp;

        hst[g][2*m]   = hvp.x;
        hst[g][2*m+1] = hvp.y;
        hbuf[(wrow + 2*m    )*72 + g*16 + n16] = (__bf16)hvp.x;
        hbuf[(wrow + 2*m + 1)*72 + g*16 + n16] = (__bf16)hvp.y;
      }
    }

    a0 = *(const bf16x8*)&hbuf[arow*72 + quad*8];
    a1 = *(const bf16x8*)&hbuf[arow*72 + 32 + quad*8];

    // ---- MLP1 ----
    #pragma unroll
    for (int c2 = 0; c2 < 2; ++c2) {
      const float bb = c2 ? b1v1 : b1v0;
      const f32x4 binit = {bb, bb, bb, bb};
      f32x4 hc = MFMA(a0, *(const bf16x8*)&w1tab[((c2*2  )*64 + lane)*8], binit);
      hc       = MFMA(a1, *(const bf16x8*)&w1tab[((c2*2+1)*64 + lane)*8], hc);
      #pragma unroll
      for (int i = 0; i < 4; ++i)
        hidbuf[(wrow + i)*40 + c2*16 + n16] = (__bf16)fmaxf(hc[i], 0.f);
    }

    // ---- MLP2: ls -> hidbuf pad (cols 32..39 as 4 floats) ----
    {
      const bf16x8 ha = *(const bf16x8*)&hidbuf[arow*40 + quad*8];
      const f32x4 b2init = {b2ln, b2ln, b2ln, b2ln};
      const f32x4 ls = MFMA(ha, W2f, b2init);
      if (n16 < 4) {
        #pragma unroll
        for (int i = 0; i < 4; ++i)
          ((float*)&hidbuf[(wrow + i)*40 + 32])[n16] = ls[i];
      }
    }

    // ---- epilogue (32 lanes): y update + scale product (log deferred) ----
    if (lane < 32) {
      const float* lsp = (const float*)&hidbuf[erow*40 + 32];
      const float lc = lsp[comp];
      const float l2 = lsp[2 + comp];
      const float s  = __logf(1.0f + __expf(l2)) + 0.001f;
      yc += lc + s * xt;
      prodS *= s;
      yst[comp*64 + erow] = yc;
      yp[t*2] = yc;
    }
  }

  // logabsdet = log(prod_t s_t) per comp, summed over comps (matches reference)
  const float ll  = __logf(prodS);
  const float llo = __shfl(ll, lane ^ 16, 64);
  if (lane < 16) lad_out[gb + wave*16 + lane] = ll + llo;
}

extern "C" void kernel_launch(void* const* d_in, const int* in_sizes, int n_in,
                              void* d_out, int out_size, void* d_ws, size_t ws_size,
                              hipStream_t stream) {
  const float* x    = (const float*)d_in[0];
  const float* z    = (const float*)d_in[1];
  const float* W_ih = (const float*)d_in[2];
  const float* W_hh = (const float*)d_in[3];
  const float* b_ih = (const float*)d_in[4];
  const float* b_hh = (const float*)d_in[5];
  const float* W1   = (const float*)d_in[6];
  const float* b1   = (const float*)d_in[7];
  const float* W2   = (const float*)d_in[8];
  const float* b2   = (const float*)d_in[9];

  float* y_out   = (float*)d_out;
  float* lad_out = y_out + (size_t)BSZ * TT * 2;

  dim3 grid(BSZ / RPB), block(BLK);
  hipLaunchKernelGGL(flow7, grid, block, 0, stream,
                     x, z, W_ih, W_hh, b_ih, b_hh, W1, b1, W2, b2,
                     y_out, lad_out);
}

// Round 4
// 240.496 us; speedup vs baseline: 4.4426x; 3.0467x over previous
//
#include <hip/hip_runtime.h>

// B=131072, T=16, D=2, H=64. 16 rows/wave, 4 waves/block.
// R9 (bisect from R8 fail): component status across rounds --
//   R5 skeleton (scalar tail, fp32 gi via gi_tab): PROVEN (84 VGPR, no scratch, 180us)
//   fused single-rcp tail (+clamps):               PROVEN in R7 (absmax 0.0625)
//   deferred logabsdet (prod, one log):            PROVEN in R7
//   f32x2 packing:        REJECTED (scratch: FETCH 25MB->1.9GB, rule #20)
//   gi->MFMA K-slot fold: REJECTED (R8 numerics fail 0.98 > 0.28)
// R9 = R5 + fused tail + deferred log only.
// Tail: hv = [h*S + Ez*(S-2)] * rcp(S*Ez+S), S=1+exp2(pre), Ez=exp2(sz);
// sz/pre clamped at 61 so inf never reaches the fused num/den (inf-inf=NaN).
#define BSZ 131072
#define TT  16
#define RPB 64
#define BLK 256

#define LOG2E      1.4426950408889634f
#define NEG_LOG2E  (-1.4426950408889634f)
#define TWO_LOG2E  2.8853900817779268f

typedef __bf16 bf16x8 __attribute__((ext_vector_type(8)));
typedef float  f32x4  __attribute__((ext_vector_type(4)));

#define MFMA(a,b,c) __builtin_amdgcn_mfma_f32_16x16x32_bf16((a),(b),(c),0,0,0)

static __device__ __forceinline__ float rcp_f(float v){ float r; asm("v_rcp_f32 %0, %1" : "=v"(r) : "v"(v)); return r; }
static __device__ __forceinline__ float exp2_f(float v){ float r; asm("v_exp_f32 %0, %1" : "=v"(r) : "v"(v)); return r; }

__global__ __launch_bounds__(BLK, 3) void flow9(
    const float* __restrict__ x,     // (B,16,2)
    const float* __restrict__ z,     // (B,64)
    const float* __restrict__ W_ih,  // (192,2)
    const float* __restrict__ W_hh,  // (192,64)
    const float* __restrict__ b_ih,  // (192)
    const float* __restrict__ b_hh,  // (192)
    const float* __restrict__ W1,    // (64,32)
    const float* __restrict__ b1,    // (32)
    const float* __restrict__ W2,    // (32,4)
    const float* __restrict__ b2,    // (4)
    float* __restrict__ y_out,       // (B,16,2)
    float* __restrict__ lad_out)     // (B)
{
  // LDS: 16384 + 4096 + 3072 + 9216 + 5120 + 512 = 38400 B (4 blocks/CU)
  __shared__ __align__(16) __bf16 whhtab[16*64*8];  // z/n-gate B-frags [f][lane][8] (pre-scaled)
  __shared__ __align__(16) __bf16 w1tab[4*64*8];    // W1 B-frags
  __shared__ __align__(16) float4 gi_tab[192];      // {Wih0, Wih1, bias, 0} (pre-scaled)
  __shared__ __align__(16) __bf16 hbuf[RPB*72];     // h bf16, stride 72; cols 64..71 pad
  __shared__ __align__(16) __bf16 hidbuf[RPB*40];   // hidden, stride 40; cols 32..39 = ls pad
  __shared__ __align__(16) float  ystate[RPB*2];    // y_{t-1} [row][comp]

  const int tid  = threadIdx.x;
  const int lane = tid & 63, wave = tid >> 6;
  const int quad = lane >> 4, n16 = lane & 15;
  const int gb   = blockIdx.x * RPB;
  const f32x4 zero = {0.f,0.f,0.f,0.f};

  // ---------- one-time staging ----------
  if (tid < 192) {  // gi_tab, pre-scaled
    const int j = tid;
    const float sc = (j < 128) ? NEG_LOG2E : TWO_LOG2E;
    const float w0 = W_ih[2*j]*sc, w1 = W_ih[2*j+1]*sc;
    const float bi = b_ih[j], bh = b_hh[j];
    gi_tab[j] = make_float4(w0, w1, ((j < 128) ? bi + bh : bi)*sc, 0.f);
  }
  // whhtab: f = (gate-1)*8 + g*2 + kt, gate 1=z (x -log2e), 2=n (x 2log2e)
  #pragma unroll
  for (int i = 0; i < 4; ++i) {
    const int f = i*4 + wave;
    const int gate = 1 + (f >> 3), g = (f >> 1) & 3, kt = f & 1;
    const float sc = (gate == 1) ? NEG_LOG2E : TWO_LOG2E;
    const float* p = W_hh + (size_t)((gate*4 + g)*16 + n16)*64 + kt*32 + quad*8;
    bf16x8 v;
    #pragma unroll
    for (int j = 0; j < 8; ++j) v[j] = (__bf16)(p[j]*sc);
    *(bf16x8*)&whhtab[(f*64 + lane)*8] = v;
  }
  { // w1tab: frag f = c2*2+kt, one per wave (unscaled)
    const int f = wave, c2 = f >> 1, kt = f & 1;
    bf16x8 v;
    #pragma unroll
    for (int j = 0; j < 8; ++j)
      v[j] = (__bf16)W1[(size_t)(kt*32 + quad*8 + j)*32 + c2*16 + n16];
    *(bf16x8*)&w1tab[(f*64 + lane)*8] = v;
  }
  if (tid < 128) ystate[tid] = 0.f;
  #pragma unroll
  for (int r4 = 0; r4 < 4; ++r4) {  // z -> hbuf (bf16)
    const int row = (tid >> 4) + r4*16, col = (tid & 15)*4;
    const float4 zv = *(const float4*)&z[(size_t)(gb + row)*64 + col];
    hbuf[row*72 + col+0] = (__bf16)zv.x; hbuf[row*72 + col+1] = (__bf16)zv.y;
    hbuf[row*72 + col+2] = (__bf16)zv.z; hbuf[row*72 + col+3] = (__bf16)zv.w;
  }

  // r-gate B-frags in regs (pre-scaled by -log2e): 8 x bf16x8 = 32 VGPR
  bf16x8 Whr[4][2];
  #pragma unroll
  for (int g = 0; g < 4; ++g)
    #pragma unroll
    for (int kt = 0; kt < 2; ++kt) {
      const float* p = W_hh + (size_t)(g*16 + n16)*64 + kt*32 + quad*8;
      bf16x8 v;
      #pragma unroll
      for (int j = 0; j < 8; ++j) v[j] = (__bf16)(p[j]*NEG_LOG2E);
      Whr[g][kt] = v;
    }
  // W2 B-frag in regs (4 VGPR)
  bf16x8 W2f;
  #pragma unroll
  for (int j = 0; j < 8; ++j)
    W2f[j] = (n16 < 4) ? (__bf16)W2[(size_t)(quad*8 + j)*4 + n16] : (__bf16)0.f;

  // h state fp32 C-layout: hst[g][i] = h[quad*4+i][g*16+n16]
  f32x4 hst[4];
  #pragma unroll
  for (int g = 0; g < 4; ++g)
    #pragma unroll
    for (int i = 0; i < 4; ++i)
      hst[g][i] = z[(size_t)(gb + wave*16 + quad*4 + i)*64 + g*16 + n16];
  float bhn[4];   // b_hh n-part, scaled (folded into cn C-init)
  #pragma unroll
  for (int g = 0; g < 4; ++g) bhn[g] = b_hh[128 + g*16 + n16]*TWO_LOG2E;
  const float b1v0 = b1[n16], b1v1 = b1[16 + n16];
  const float b2ln = (n16 < 4) ? b2[n16] : 0.f;

  __syncthreads();  // only barrier

  const int arow = wave*16 + n16;
  bf16x8 a0 = *(const bf16x8*)&hbuf[arow*72 + quad*8];
  bf16x8 a1 = *(const bf16x8*)&hbuf[arow*72 + 32 + quad*8];

  // epilogue: 32 lanes, comp = lane>>4, row = lane&15
  const int erow = wave*16 + (lane & 15);
  const int comp = (lane >> 4) & 1;
  const float* xp = x + (size_t)(gb + erow)*(TT*2) + comp;
  float*       yp = y_out + (size_t)(gb + erow)*(TT*2) + comp;
  float yc = 0.f, prodS = 1.0f;

  #pragma unroll 1
  for (int t = 0; t < TT; ++t) {
    const float xt = (lane < 32) ? xp[t*2] : 0.f;   // issue global load early
    float ys0[4], ys1[4];
    #pragma unroll
    for (int i = 0; i < 4; ++i) {
      const float2 yv = *(const float2*)&ystate[(wave*16 + quad*4 + i)*2];
      ys0[i] = yv.x; ys1[i] = yv.y;
    }

    // ---- GRU per col-group g (all pre-activations in scaled domain) ----
    #pragma unroll
    for (int g = 0; g < 4; ++g) {
      const bf16x8 bz0 = *(const bf16x8*)&whhtab[((g*2    )*64 + lane)*8];
      const bf16x8 bz1 = *(const bf16x8*)&whhtab[((g*2 + 1)*64 + lane)*8];
      const bf16x8 bn0 = *(const bf16x8*)&whhtab[((8 + g*2    )*64 + lane)*8];
      const bf16x8 bn1 = *(const bf16x8*)&whhtab[((8 + g*2 + 1)*64 + lane)*8];
      f32x4 cr = MFMA(a0, Whr[g][0], zero); cr = MFMA(a1, Whr[g][1], cr);
      f32x4 cz = MFMA(a0, bz0, zero);       cz = MFMA(a1, bz1, cz);
      const f32x4 cninit = {bhn[g], bhn[g], bhn[g], bhn[g]};
      f32x4 cn = MFMA(a0, bn0, cninit);     cn = MFMA(a1, bn1, cn);
      const float4 Tr = gi_tab[      g*16 + n16];
      const float4 Tz = gi_tab[ 64 + g*16 + n16];
      const float4 Tn = gi_tab[128 + g*16 + n16];
      #pragma unroll
      for (int i = 0; i < 4; ++i) {
        const float sr  = fmaf(Tr.x, ys0[i], fmaf(Tr.y, ys1[i], Tr.z)) + cr[i]; // = -log2e*vr
        const float sz  = fminf(fmaf(Tz.x, ys0[i], fmaf(Tz.y, ys1[i], Tz.z)) + cz[i], 61.f);
        const float gin = fmaf(Tn.x, ys0[i], fmaf(Tn.y, ys1[i], Tn.z));         // = 2log2e*(..)
        const float r   = rcp_f(1.0f + exp2_f(sr));                             // sigmoid(vr)
        const float pre = fminf(fmaf(r, cn[i], gin), 61.f);                     // = 2log2e*vn
        // fused tail: u = 1/(1+Ez), tanh = (S-2)/S; hv = u*h + (1-u)*tanh
        //           = [h*S + Ez*(S-2)] / [S*(Ez+1)]
        const float Ez  = exp2_f(sz);
        const float En  = exp2_f(pre);
        const float S   = En + 1.0f;
        const float num = fmaf(S, hst[g][i] + Ez, Ez * -2.0f);
        const float den = fmaf(S, Ez, S);
        const float hv  = num * rcp_f(den);
        hst[g][i] = hv;
        hbuf[(wave*16 + quad*4 + i)*72 + g*16 + n16] = (__bf16)hv;
      }
    }

    a0 = *(const bf16x8*)&hbuf[arow*72 + quad*8];
    a1 = *(const bf16x8*)&hbuf[arow*72 + 32 + quad*8];

    // ---- MLP1 ----
    #pragma unroll
    for (int c2 = 0; c2 < 2; ++c2) {
      const float bb = c2 ? b1v1 : b1v0;
      const f32x4 binit = {bb, bb, bb, bb};
      f32x4 hc = MFMA(a0, *(const bf16x8*)&w1tab[((c2*2  )*64 + lane)*8], binit);
      hc       = MFMA(a1, *(const bf16x8*)&w1tab[((c2*2+1)*64 + lane)*8], hc);
      #pragma unroll
      for (int i = 0; i < 4; ++i)
        hidbuf[(wave*16 + quad*4 + i)*40 + c2*16 + n16] = (__bf16)fmaxf(hc[i], 0.f);
    }

    // ---- MLP2: ls -> hidbuf pad (cols 32..39 as 4 floats) ----
    {
      const bf16x8 ha = *(const bf16x8*)&hidbuf[arow*40 + quad*8];
      const f32x4 b2init = {b2ln, b2ln, b2ln, b2ln};
      const f32x4 ls = MFMA(ha, W2f, b2init);
      if (n16 < 4) {
        #pragma unroll
        for (int i = 0; i < 4; ++i)
          ((float*)&hidbuf[(wave*16 + quad*4 + i)*40 + 32])[n16] = ls[i];
      }
    }

    // ---- epilogue (32 lanes): y update + scale product (log deferred) ----
    if (lane < 32) {
      const float* lsp = (const float*)&hidbuf[erow*40 + 32];
      const float lc = lsp[comp];
      const float l2 = lsp[2 + comp];
      const float s  = __logf(1.0f + __expf(l2)) + 0.001f;
      yc += lc + s * xt;
      prodS *= s;
      ystate[erow*2 + comp] = yc;
      yp[t*2] = yc;
    }
  }

  // logabsdet = log(prod_t s_t) per comp, summed over comps (matches reference)
  const float ll  = __logf(prodS);
  const float llo = __shfl(ll, lane ^ 16, 64);
  if (lane < 16) lad_out[gb + wave*16 + lane] = ll + llo;
}

extern "C" void kernel_launch(void* const* d_in, const int* in_sizes, int n_in,
                              void* d_out, int out_size, void* d_ws, size_t ws_size,
                              hipStream_t stream) {
  const float* x    = (const float*)d_in[0];
  const float* z    = (const float*)d_in[1];
  const float* W_ih = (const float*)d_in[2];
  const float* W_hh = (const float*)d_in[3];
  const float* b_ih = (const float*)d_in[4];
  const float* b_hh = (const float*)d_in[5];
  const float* W1   = (const float*)d_in[6];
  const float* b1   = (const float*)d_in[7];
  const float* W2   = (const float*)d_in[8];
  const float* b2   = (const float*)d_in[9];

  float* y_out   = (float*)d_out;
  float* lad_out = y_out + (size_t)BSZ * TT * 2;

  dim3 grid(BSZ / RPB), block(BLK);
  hipLaunchKernelGGL(flow9, grid, block, 0, stream,
                     x, z, W_ih, W_hh, b_ih, b_hh, W1, b1, W2, b2,
                     y_out, lad_out);
}